// Round 1
// baseline (581.383 us; speedup 1.0000x reference)
//
#include <hip/hip_runtime.h>

typedef __bf16 bf16x8 __attribute__((ext_vector_type(8)));
typedef float f32x4 __attribute__((ext_vector_type(4)));

// ---------------- sizes ----------------
// B=8, LAT=512, CIN=F=256, Hin=Win=64, H=W=128, K=3
// ws layout (bytes):
//   xu  NHWC bf16 [8][128][128][256]  : off 0          size 67108864
//   y1  NHWC bf16 [8][128][128][256]  : off 67108864   size 67108864
//   wm1 bf16 [8][256][9][256]         : off 134217728  size 9437184
//   wm2 bf16 [8][256][9][256]         : off 143654912  size 9437184
//   sbuf f32 [2][8][256]              : off 153092096  size 16384

// ---------------- styles: s = istyle @ ws^T + bs ----------------
__global__ void style_kernel(const float* __restrict__ istyle,
                             const float* __restrict__ ws1, const float* __restrict__ bs1,
                             const float* __restrict__ ws2, const float* __restrict__ bs2,
                             float* __restrict__ sbuf) {
    int b = blockIdx.x;          // 0..7
    int which = blockIdx.y;      // 0..1
    int c = threadIdx.x;         // 0..255
    const float* ws = which ? ws2 : ws1;
    const float* bs = which ? bs2 : bs1;
    __shared__ float st[512];
    for (int i = threadIdx.x; i < 512; i += 256) st[i] = istyle[b * 512 + i];
    __syncthreads();
    float acc = bs[c];
    const float* wr = ws + (size_t)c * 512;
    for (int l = 0; l < 512; ++l) acc += st[l] * wr[l];
    sbuf[((size_t)which * 8 + b) * 256 + c] = acc;
}

// ---------------- modulate + demodulate weights -> bf16 [b][o][tap][c] ----------------
__global__ void modw_kernel(const float* __restrict__ w1, const float* __restrict__ w2,
                            const float* __restrict__ sbuf,
                            __bf16* __restrict__ wm1, __bf16* __restrict__ wm2) {
    int which = blockIdx.y;
    int b = blockIdx.x >> 8;
    int o = blockIdx.x & 255;
    int c = threadIdx.x;
    const float* w = which ? w2 : w1;
    __bf16* wm = which ? wm2 : wm1;
    float sm = sbuf[((size_t)which * 8 + b) * 256 + c] + 1.0f;
    float v[9];
    float ss = 0.f;
    const float* wr = w + ((size_t)o * 256 + c) * 9;
#pragma unroll
    for (int t = 0; t < 9; ++t) { v[t] = wr[t] * sm; ss += v[t] * v[t]; }
    __shared__ float red[256];
    red[c] = ss;
    __syncthreads();
    for (int s = 128; s > 0; s >>= 1) {
        if (c < s) red[c] += red[c + s];
        __syncthreads();
    }
    float d = rsqrtf(red[0] + 1e-8f);
#pragma unroll
    for (int t = 0; t < 9; ++t)
        wm[(((size_t)(b * 256 + o) * 9 + t) * 256) + c] = (__bf16)(v[t] * d);
}

// ---------------- bilinear 2x upsample NCHW f32 -> NHWC bf16 ----------------
__global__ void upsample_kernel(const float* __restrict__ x, __bf16* __restrict__ xu) {
    int ct = blockIdx.x;   // 0..7  (channel tile of 32)
    int y  = blockIdx.y;   // 0..127 (output row)
    int b  = blockIdx.z;   // 0..7
    int c0 = ct * 32;
    __shared__ float up[32 * 132];
    int tid = threadIdx.x;

    int j = y >> 1;
    int y0, y1; float wy0, wy1;
    if (y & 1) { y0 = j; y1 = (j + 1 < 64) ? j + 1 : 63; wy0 = 0.75f; wy1 = 0.25f; }
    else       { y0 = (j - 1 >= 0) ? j - 1 : 0; y1 = j; wy0 = 0.25f; wy1 = 0.75f; }

    int c  = tid >> 3;          // 0..31
    int xs = (tid & 7) * 16;
    const float* row0 = x + ((size_t)(b * 256 + c0 + c) * 64 + y0) * 64;
    const float* row1 = x + ((size_t)(b * 256 + c0 + c) * 64 + y1) * 64;
#pragma unroll
    for (int k = 0; k < 16; ++k) {
        int xo = xs + k;
        int i = xo >> 1;
        int x0, x1; float wx0, wx1;
        if (xo & 1) { x0 = i; x1 = (i + 1 < 64) ? i + 1 : 63; wx0 = 0.75f; wx1 = 0.25f; }
        else        { x0 = (i - 1 >= 0) ? i - 1 : 0; x1 = i; wx0 = 0.25f; wx1 = 0.75f; }
        float v0 = wx0 * row0[x0] + wx1 * row0[x1];
        float v1 = wx0 * row1[x0] + wx1 * row1[x1];
        up[c * 132 + xo] = wy0 * v0 + wy1 * v1;
    }
    __syncthreads();
    int xo = tid >> 1, half = tid & 1;
    union { __bf16 v[8]; uint4 u; } pk;
#pragma unroll
    for (int g = 0; g < 2; ++g) {
#pragma unroll
        for (int i = 0; i < 8; ++i)
            pk.v[i] = (__bf16)up[(half * 16 + g * 8 + i) * 132 + xo];
        *(uint4*)(xu + (((size_t)(b * 128) + y) * 128 + xo) * 256 + c0 + half * 16 + g * 8) = pk.u;
    }
}

// ---------------- implicit-GEMM modulated conv 3x3 ----------------
// Per block: one batch b, o-tile of 128 (mtile), one output image row (128 pixels).
// GEMM: M=128 out-ch (A = wm[b]), N=128 pixels (B = patches from NHWC input), K=9*256 (tap,c)
// PHASE 1: out = leaky -> NHWC bf16 (y1).  PHASE 2: out = leaky -> NCHW f32 (d_out).
template <int PHASE>
__global__ __launch_bounds__(256, 2) void conv_kernel(
    const __bf16* __restrict__ in,    // NHWC [8][128][128][256]
    const __bf16* __restrict__ wm,    // [8][256][9][256]
    float* __restrict__ outf,         // PHASE 2
    __bf16* __restrict__ outb) {      // PHASE 1
    __shared__ __bf16 Al[128 * 40];
    __shared__ __bf16 Bl[128 * 40];
    const int tid   = threadIdx.x;
    const int b     = blockIdx.y;
    const int mtile = blockIdx.x & 1;
    const int yrow  = blockIdx.x >> 1;
    const int om    = mtile * 128;
    const int lane  = tid & 63;
    const int wv    = tid >> 6;
    const int wo    = (wv >> 1) * 64;   // wave o-offset
    const int wn    = (wv & 1) * 64;    // wave pixel-offset
    const int arow  = lane & 15;
    const int koff  = (lane >> 4) * 8;

    f32x4 acc[4][4] = {};

    for (int tap = 0; tap < 9; ++tap) {
        const int ky = tap / 3, kx = tap % 3;
        const int yy = yrow + ky - 1;
        const bool vrow = ((unsigned)yy < 128u);
        const __bf16* inrow = in + ((size_t)(b * 128 + yy) * 128) * 256;
        const __bf16* wrow  = wm + (((size_t)(b * 256 + om) * 9 + tap) * 256);
        for (int c0 = 0; c0 < 256; c0 += 32) {
#pragma unroll
            for (int p = 0; p < 2; ++p) {
                int idx = p * 256 + tid;
                int r  = idx >> 2;
                int ci = (idx & 3) * 8;
                // A: weights, always valid
                uint4 av = *(const uint4*)(wrow + (size_t)r * 9 * 256 + c0 + ci);
                *(uint4*)(Al + r * 40 + ci) = av;
                // B: shifted input row with zero padding
                int xx = r + kx - 1;
                uint4 bv = make_uint4(0, 0, 0, 0);
                if (vrow && (unsigned)xx < 128u)
                    bv = *(const uint4*)(inrow + (size_t)xx * 256 + c0 + ci);
                *(uint4*)(Bl + r * 40 + ci) = bv;
            }
            __syncthreads();
            bf16x8 af[4], bfr[4];
#pragma unroll
            for (int i = 0; i < 4; ++i) {
                af[i]  = *(const bf16x8*)(Al + (wo + i * 16 + arow) * 40 + koff);
                bfr[i] = *(const bf16x8*)(Bl + (wn + i * 16 + arow) * 40 + koff);
            }
#pragma unroll
            for (int i = 0; i < 4; ++i)
#pragma unroll
                for (int j = 0; j < 4; ++j)
                    acc[i][j] = __builtin_amdgcn_mfma_f32_16x16x32_bf16(af[i], bfr[j], acc[i][j], 0, 0, 0);
            __syncthreads();
        }
    }

    // epilogue: leaky relu + store
#pragma unroll
    for (int i = 0; i < 4; ++i) {
#pragma unroll
        for (int j = 0; j < 4; ++j) {
            int o_base = om + wo + i * 16 + (lane >> 4) * 4;
            int n      = wn + j * 16 + (lane & 15);
            if (PHASE == 1) {
                union { __bf16 v[4]; uint2 u; } pk;
#pragma unroll
                for (int r = 0; r < 4; ++r) {
                    float t = acc[i][j][r];
                    t = (t > 0.f) ? t : 0.2f * t;
                    pk.v[r] = (__bf16)t;
                }
                *(uint2*)(outb + (((size_t)(b * 128) + yrow) * 128 + n) * 256 + o_base) = pk.u;
            } else {
#pragma unroll
                for (int r = 0; r < 4; ++r) {
                    float t = acc[i][j][r];
                    t = (t > 0.f) ? t : 0.2f * t;
                    outf[(((size_t)b * 256 + o_base + r) * 128 + yrow) * 128 + n] = t;
                }
            }
        }
    }
}

extern "C" void kernel_launch(void* const* d_in, const int* in_sizes, int n_in,
                              void* d_out, int out_size, void* d_ws, size_t ws_size,
                              hipStream_t stream) {
    const float* x      = (const float*)d_in[0];
    const float* istyle = (const float*)d_in[1];
    const float* ws1    = (const float*)d_in[2];
    const float* bs1    = (const float*)d_in[3];
    const float* w1     = (const float*)d_in[4];
    const float* ws2    = (const float*)d_in[5];
    const float* bs2    = (const float*)d_in[6];
    const float* w2     = (const float*)d_in[7];
    float* out = (float*)d_out;

    char* ws = (char*)d_ws;
    __bf16* xu   = (__bf16*)(ws);
    __bf16* y1   = (__bf16*)(ws + 67108864);
    __bf16* wm1  = (__bf16*)(ws + 134217728);
    __bf16* wm2  = (__bf16*)(ws + 143654912);
    float*  sbuf = (float*)(ws + 153092096);

    style_kernel<<<dim3(8, 2), 256, 0, stream>>>(istyle, ws1, bs1, ws2, bs2, sbuf);
    modw_kernel<<<dim3(2048, 2), 256, 0, stream>>>(w1, w2, sbuf, wm1, wm2);
    upsample_kernel<<<dim3(8, 128, 8), 256, 0, stream>>>(x, xu);
    conv_kernel<1><<<dim3(256, 8), 256, 0, stream>>>(xu, wm1, nullptr, y1);
    conv_kernel<2><<<dim3(256, 8), 256, 0, stream>>>(y1, wm2, out, nullptr);
}

// Round 2
// 418.204 us; speedup vs baseline: 1.3902x; 1.3902x over previous
//
#include <hip/hip_runtime.h>

typedef __bf16 bf16x8 __attribute__((ext_vector_type(8)));
typedef float f32x4 __attribute__((ext_vector_type(4)));

// ---------------- sizes ----------------
// B=8, LAT=512, CIN=F=256, Hin=Win=64, H=W=128, K=3
// ws layout (bytes):
//   xu_p NHWC bf16 [8][130][130][256] : off 0          size 69222400
//   y1_p NHWC bf16 [8][130][130][256] : off 69222400   size 69222400
//   wm   bf16 [8][256][9][256]        : off 138444800  size 9437184   (reused for both convs)
//   sbuf f32 [2][8][256]              : off 147881984  size 16384
// total 147898368 <= previous working 153 MB footprint

// ---------------- styles: s = istyle @ ws^T + bs ----------------
__global__ void style_kernel(const float* __restrict__ istyle,
                             const float* __restrict__ ws1, const float* __restrict__ bs1,
                             const float* __restrict__ ws2, const float* __restrict__ bs2,
                             float* __restrict__ sbuf) {
    int b = blockIdx.x;          // 0..7
    int which = blockIdx.y;      // 0..1
    int c = threadIdx.x;         // 0..255
    const float* ws = which ? ws2 : ws1;
    const float* bs = which ? bs2 : bs1;
    __shared__ float st[512];
    for (int i = threadIdx.x; i < 512; i += 256) st[i] = istyle[b * 512 + i];
    __syncthreads();
    float acc = bs[c];
    const float* wr = ws + (size_t)c * 512;
    for (int l = 0; l < 512; ++l) acc += st[l] * wr[l];
    sbuf[((size_t)which * 8 + b) * 256 + c] = acc;
}

// ---------------- modulate + demodulate weights -> bf16 [b][o][tap][c] ----------------
__global__ void modw_kernel(const float* __restrict__ w, const float* __restrict__ s,
                            __bf16* __restrict__ wm) {
    int b = blockIdx.x >> 8;
    int o = blockIdx.x & 255;
    int c = threadIdx.x;
    float sm = s[(size_t)b * 256 + c] + 1.0f;
    float v[9];
    float ss = 0.f;
    const float* wr = w + ((size_t)o * 256 + c) * 9;
#pragma unroll
    for (int t = 0; t < 9; ++t) { v[t] = wr[t] * sm; ss += v[t] * v[t]; }
    __shared__ float red[256];
    red[c] = ss;
    __syncthreads();
    for (int sh = 128; sh > 0; sh >>= 1) {
        if (c < sh) red[c] += red[c + sh];
        __syncthreads();
    }
    float d = rsqrtf(red[0] + 1e-8f);
#pragma unroll
    for (int t = 0; t < 9; ++t)
        wm[(((size_t)(b * 256 + o) * 9 + t) * 256) + c] = (__bf16)(v[t] * d);
}

// ---------------- zero the 1-pixel border of both padded buffers ----------------
__global__ void zeropad_kernel(__bf16* __restrict__ xu, __bf16* __restrict__ y1) {
    int p = blockIdx.x;      // 0..515
    int b = blockIdx.y;      // 0..7
    __bf16* buf = blockIdx.z ? y1 : xu;
    int y, x;
    if (p < 130)      { y = 0;           x = p; }
    else if (p < 260) { y = 129;         x = p - 130; }
    else if (p < 388) { y = p - 260 + 1; x = 0; }
    else              { y = p - 388 + 1; x = 129; }
    uint4 z = make_uint4(0, 0, 0, 0);
    *(uint4*)(buf + (((size_t)b * 130 + y) * 130 + x) * 256 + threadIdx.x * 8) = z;
}

// ---------------- bilinear 2x upsample NCHW f32 -> padded NHWC bf16 ----------------
__global__ void upsample_kernel(const float* __restrict__ x, __bf16* __restrict__ xu) {
    int ct = blockIdx.x;   // 0..7  (channel tile of 32)
    int y  = blockIdx.y;   // 0..127 (output row)
    int b  = blockIdx.z;   // 0..7
    int c0 = ct * 32;
    __shared__ float up[32 * 132];
    int tid = threadIdx.x;

    int j = y >> 1;
    int y0, y1; float wy0, wy1;
    if (y & 1) { y0 = j; y1 = (j + 1 < 64) ? j + 1 : 63; wy0 = 0.75f; wy1 = 0.25f; }
    else       { y0 = (j - 1 >= 0) ? j - 1 : 0; y1 = j; wy0 = 0.25f; wy1 = 0.75f; }

    int c  = tid >> 3;          // 0..31
    int xs = (tid & 7) * 16;
    const float* row0 = x + ((size_t)(b * 256 + c0 + c) * 64 + y0) * 64;
    const float* row1 = x + ((size_t)(b * 256 + c0 + c) * 64 + y1) * 64;
#pragma unroll
    for (int k = 0; k < 16; ++k) {
        int xo = xs + k;
        int i = xo >> 1;
        int x0, x1; float wx0, wx1;
        if (xo & 1) { x0 = i; x1 = (i + 1 < 64) ? i + 1 : 63; wx0 = 0.75f; wx1 = 0.25f; }
        else        { x0 = (i - 1 >= 0) ? i - 1 : 0; x1 = i; wx0 = 0.25f; wx1 = 0.75f; }
        float v0 = wx0 * row0[x0] + wx1 * row0[x1];
        float v1 = wx0 * row1[x0] + wx1 * row1[x1];
        up[c * 132 + xo] = wy0 * v0 + wy1 * v1;
    }
    __syncthreads();
    int xo = tid >> 1, half = tid & 1;
    union { __bf16 v[8]; uint4 u; } pk;
#pragma unroll
    for (int g = 0; g < 2; ++g) {
#pragma unroll
        for (int i = 0; i < 8; ++i)
            pk.v[i] = (__bf16)up[(half * 16 + g * 8 + i) * 132 + xo];
        *(uint4*)(xu + (((size_t)(b * 130) + y + 1) * 130 + xo + 1) * 256 + c0 + half * 16 + g * 8) = pk.u;
    }
}

// ---------------- implicit-GEMM modulated conv 3x3 (m97 structure) ----------------
// Per block: batch b, o-tile of 128 (mtile), one output row (128 pixels).
// GEMM: M=128 out-ch (A = wm[b]), N=128 pixels (B = padded NHWC patches), K=9*256.
// BK=64, global_load_lds width 16 with XOR-chunk swizzle (T2 both-sides).
// PHASE 1: leaky -> padded NHWC bf16 (y1_p).  PHASE 2: leaky -> NCHW f32 (d_out).
template <int PHASE>
__global__ __launch_bounds__(256, 3) void conv_kernel(
    const __bf16* __restrict__ in,    // padded NHWC [8][130][130][256]
    const __bf16* __restrict__ wm,    // [8][256][9][256]
    float* __restrict__ outf,
    __bf16* __restrict__ outb) {
    __shared__ __bf16 Al[128 * 64];
    __shared__ __bf16 Bl[128 * 64];
    const int tid   = threadIdx.x;
    // XCD-bijective swizzle: 2048 blocks = 8 XCDs x 256; one batch per XCD.
    const int bid   = blockIdx.x;
    const int swz   = (bid & 7) * 256 + (bid >> 3);
    const int b     = swz >> 8;
    const int bx    = swz & 255;
    const int yrow  = bx >> 1;
    const int mtile = bx & 1;
    const int om    = mtile * 128;
    const int lane  = tid & 63;
    const int wv    = tid >> 6;
    const int wo    = (wv >> 1) * 64;   // wave o-offset in tile
    const int wn    = (wv & 1) * 64;    // wave pixel-offset in tile
    // staging decomposition: lane -> (row-in-8, 16B chunk), source chunk XOR-swizzled
    const int lr    = lane >> 3;        // 0..7  row within 8-row slab
    const int lc    = lane & 7;         // 16B chunk within 128B row
    const int swzc  = (lc ^ lr) * 8;    // element offset of source chunk
    // fragment-read lane decomposition
    const int arow  = lane & 15;
    const int cgb   = lane >> 4;        // 0..3

    const size_t wmbase = ((size_t)(b * 256 + om + wv * 32 + lr) * 9) * 256 + swzc;
    const size_t inbase = (size_t)b * 130 * 130 * 256 + (size_t)(wv * 32 + lr) * 256 + swzc;

    f32x4 acc[4][4] = {};

    for (int tap = 0; tap < 9; ++tap) {
        const int ky = tap / 3, kx = tap % 3;
        const size_t inrow = inbase + (size_t)((yrow + ky) * 130 + kx) * 256;
        const size_t wrow  = wmbase + (size_t)tap * 256;
        for (int c0 = 0; c0 < 256; c0 += 64) {
#pragma unroll
            for (int q = 0; q < 4; ++q) {
                __builtin_amdgcn_global_load_lds(
                    (const __attribute__((address_space(1))) unsigned int*)(wm + wrow + (size_t)q * 8 * 9 * 256 + c0),
                    (__attribute__((address_space(3))) unsigned int*)(Al + (wv * 32 + q * 8) * 64),
                    16, 0, 0);
                __builtin_amdgcn_global_load_lds(
                    (const __attribute__((address_space(1))) unsigned int*)(in + inrow + (size_t)q * 8 * 256 + c0),
                    (__attribute__((address_space(3))) unsigned int*)(Bl + (wv * 32 + q * 8) * 64),
                    16, 0, 0);
            }
            __syncthreads();
#pragma unroll
            for (int ks = 0; ks < 2; ++ks) {
                const int cg = ks * 4 + cgb;    // 16B chunk index 0..7 in K
                bf16x8 af[4], bfr[4];
#pragma unroll
                for (int i = 0; i < 4; ++i) {
                    int ra = wo + i * 16 + arow;
                    af[i]  = *(const bf16x8*)((const char*)Al + ra * 128 + ((cg ^ (ra & 7)) * 16));
                    int rb = wn + i * 16 + arow;
                    bfr[i] = *(const bf16x8*)((const char*)Bl + rb * 128 + ((cg ^ (rb & 7)) * 16));
                }
#pragma unroll
                for (int i = 0; i < 4; ++i)
#pragma unroll
                    for (int j = 0; j < 4; ++j)
                        acc[i][j] = __builtin_amdgcn_mfma_f32_16x16x32_bf16(af[i], bfr[j], acc[i][j], 0, 0, 0);
            }
            __syncthreads();
        }
    }

    // epilogue: leaky relu + store
#pragma unroll
    for (int i = 0; i < 4; ++i) {
#pragma unroll
        for (int j = 0; j < 4; ++j) {
            int o_base = om + wo + i * 16 + (lane >> 4) * 4;
            int n      = wn + j * 16 + (lane & 15);
            if (PHASE == 1) {
                union { __bf16 v[4]; uint2 u; } pk;
#pragma unroll
                for (int r = 0; r < 4; ++r) {
                    float t = acc[i][j][r];
                    t = (t > 0.f) ? t : 0.2f * t;
                    pk.v[r] = (__bf16)t;
                }
                *(uint2*)(outb + (((size_t)(b * 130) + yrow + 1) * 130 + n + 1) * 256 + o_base) = pk.u;
            } else {
#pragma unroll
                for (int r = 0; r < 4; ++r) {
                    float t = acc[i][j][r];
                    t = (t > 0.f) ? t : 0.2f * t;
                    outf[(((size_t)b * 256 + o_base + r) * 128 + yrow) * 128 + n] = t;
                }
            }
        }
    }
}

extern "C" void kernel_launch(void* const* d_in, const int* in_sizes, int n_in,
                              void* d_out, int out_size, void* d_ws, size_t ws_size,
                              hipStream_t stream) {
    const float* x      = (const float*)d_in[0];
    const float* istyle = (const float*)d_in[1];
    const float* ws1    = (const float*)d_in[2];
    const float* bs1    = (const float*)d_in[3];
    const float* w1     = (const float*)d_in[4];
    const float* ws2    = (const float*)d_in[5];
    const float* bs2    = (const float*)d_in[6];
    const float* w2     = (const float*)d_in[7];
    float* out = (float*)d_out;

    char* ws = (char*)d_ws;
    __bf16* xu_p = (__bf16*)(ws);
    __bf16* y1_p = (__bf16*)(ws + 69222400);
    __bf16* wm   = (__bf16*)(ws + 138444800);
    float*  sbuf = (float*)(ws + 147881984);

    style_kernel<<<dim3(8, 2), 256, 0, stream>>>(istyle, ws1, bs1, ws2, bs2, sbuf);
    zeropad_kernel<<<dim3(516, 8, 2), 32, 0, stream>>>(xu_p, y1_p);
    upsample_kernel<<<dim3(8, 128, 8), 256, 0, stream>>>(x, xu_p);
    modw_kernel<<<dim3(2048), 256, 0, stream>>>(w1, sbuf, wm);
    conv_kernel<1><<<dim3(2048), 256, 0, stream>>>(xu_p, wm, nullptr, y1_p);
    modw_kernel<<<dim3(2048), 256, 0, stream>>>(w2, sbuf + 2048, wm);
    conv_kernel<2><<<dim3(2048), 256, 0, stream>>>(y1_p, wm, out, nullptr);
}

// Round 3
// 397.674 us; speedup vs baseline: 1.4620x; 1.0516x over previous
//
#include <hip/hip_runtime.h>

typedef __bf16 bf16x8 __attribute__((ext_vector_type(8)));
typedef float f32x4 __attribute__((ext_vector_type(4)));

// ---------------- sizes ----------------
// B=8, LAT=512, CIN=F=256, Hin=Win=64, H=W=128, K=3
// ws layout (bytes):
//   xu_p NHWC bf16 [8][130][130][256] : off 0          size 69222400
//   y1_p NHWC bf16 [8][130][130][256] : off 69222400   size 69222400
//   wm   bf16 [8][256][9][256]        : off 138444800  size 9437184   (reused)
//   sbuf f32 [2][8][256]              : off 147881984  size 16384

#define GLDS(gsrc, ldst) __builtin_amdgcn_global_load_lds( \
    (const __attribute__((address_space(1))) unsigned int*)(gsrc), \
    (__attribute__((address_space(3))) unsigned int*)(ldst), 16, 0, 0)

#define MFMA(a, b, c) __builtin_amdgcn_mfma_f32_16x16x32_bf16((a), (b), (c), 0, 0, 0)

// ---------------- styles ----------------
__global__ void style_kernel(const float* __restrict__ istyle,
                             const float* __restrict__ ws1, const float* __restrict__ bs1,
                             const float* __restrict__ ws2, const float* __restrict__ bs2,
                             float* __restrict__ sbuf) {
    int b = blockIdx.x;
    int which = blockIdx.y;
    int c = threadIdx.x;
    const float* ws = which ? ws2 : ws1;
    const float* bs = which ? bs2 : bs1;
    __shared__ float st[512];
    for (int i = threadIdx.x; i < 512; i += 256) st[i] = istyle[b * 512 + i];
    __syncthreads();
    float acc = bs[c];
    const float* wr = ws + (size_t)c * 512;
    for (int l = 0; l < 512; ++l) acc += st[l] * wr[l];
    sbuf[((size_t)which * 8 + b) * 256 + c] = acc;
}

// ---------------- modulate + demodulate -> bf16 [b][o][tap][c] ----------------
__global__ void modw_kernel(const float* __restrict__ w, const float* __restrict__ s,
                            __bf16* __restrict__ wm) {
    int b = blockIdx.x >> 8;
    int o = blockIdx.x & 255;
    int c = threadIdx.x;
    float sm = s[(size_t)b * 256 + c] + 1.0f;
    float v[9];
    float ss = 0.f;
    const float* wr = w + ((size_t)o * 256 + c) * 9;
#pragma unroll
    for (int t = 0; t < 9; ++t) { v[t] = wr[t] * sm; ss += v[t] * v[t]; }
    __shared__ float red[256];
    red[c] = ss;
    __syncthreads();
    for (int sh = 128; sh > 0; sh >>= 1) {
        if (c < sh) red[c] += red[c + sh];
        __syncthreads();
    }
    float d = rsqrtf(red[0] + 1e-8f);
#pragma unroll
    for (int t = 0; t < 9; ++t)
        wm[(((size_t)(b * 256 + o) * 9 + t) * 256) + c] = (__bf16)(v[t] * d);
}

// ---------------- zero the 1-pixel border ----------------
__global__ void zeropad_kernel(__bf16* __restrict__ xu, __bf16* __restrict__ y1) {
    int p = blockIdx.x;
    int b = blockIdx.y;
    __bf16* buf = blockIdx.z ? y1 : xu;
    int y, x;
    if (p < 130)      { y = 0;           x = p; }
    else if (p < 260) { y = 129;         x = p - 130; }
    else if (p < 388) { y = p - 260 + 1; x = 0; }
    else              { y = p - 388 + 1; x = 129; }
    uint4 z = make_uint4(0, 0, 0, 0);
    *(uint4*)(buf + (((size_t)b * 130 + y) * 130 + x) * 256 + threadIdx.x * 8) = z;
}

// ---------------- bilinear 2x upsample NCHW f32 -> padded NHWC bf16 ----------------
__global__ void upsample_kernel(const float* __restrict__ x, __bf16* __restrict__ xu) {
    int ct = blockIdx.x;
    int y  = blockIdx.y;
    int b  = blockIdx.z;
    int c0 = ct * 32;
    __shared__ float up[32 * 132];
    int tid = threadIdx.x;

    int j = y >> 1;
    int y0, y1; float wy0, wy1;
    if (y & 1) { y0 = j; y1 = (j + 1 < 64) ? j + 1 : 63; wy0 = 0.75f; wy1 = 0.25f; }
    else       { y0 = (j - 1 >= 0) ? j - 1 : 0; y1 = j; wy0 = 0.25f; wy1 = 0.75f; }

    int c  = tid >> 3;
    int xs = (tid & 7) * 16;
    const float* row0 = x + ((size_t)(b * 256 + c0 + c) * 64 + y0) * 64;
    const float* row1 = x + ((size_t)(b * 256 + c0 + c) * 64 + y1) * 64;
#pragma unroll
    for (int k = 0; k < 16; ++k) {
        int xo = xs + k;
        int i = xo >> 1;
        int x0, x1; float wx0, wx1;
        if (xo & 1) { x0 = i; x1 = (i + 1 < 64) ? i + 1 : 63; wx0 = 0.75f; wx1 = 0.25f; }
        else        { x0 = (i - 1 >= 0) ? i - 1 : 0; x1 = i; wx0 = 0.25f; wx1 = 0.75f; }
        float v0 = wx0 * row0[x0] + wx1 * row0[x1];
        float v1 = wx0 * row1[x0] + wx1 * row1[x1];
        up[c * 132 + xo] = wy0 * v0 + wy1 * v1;
    }
    __syncthreads();
    int xo = tid >> 1, half = tid & 1;
    union { __bf16 v[8]; uint4 u; } pk;
#pragma unroll
    for (int g = 0; g < 2; ++g) {
#pragma unroll
        for (int i = 0; i < 8; ++i)
            pk.v[i] = (__bf16)up[(half * 16 + g * 8 + i) * 132 + xo];
        *(uint4*)(xu + (((size_t)(b * 130) + y + 1) * 130 + xo + 1) * 256 + c0 + half * 16 + g * 8) = pk.u;
    }
}

// ---------------- implicit-GEMM modulated conv, 256x256 tile, 8-phase schedule ----------------
// Per block: batch b, 2 output rows (256 pixels), all 256 out-channels.
// M=256 (A=wm[b]), N=256 (2 rows x 128 px), K=2304 (9 taps x 256 ch), BK=64 -> 36 K-tiles.
// 8 waves (2M x 4N), per-wave output 128x64, acc[8][4] f32x4.
// LDS: 2 dbuf x (A 256x64 + B 256x64) bf16 = 128 KB. XOR-chunk swizzle (validated, 0 conflicts).
// Per K-tile: 8 stage issues for tile t+1: ph0:{B0,B1} ph1:{B2,B3} ph2:{A0,A2} ph3:{A1,A3}.
// Counted waits: vmcnt(2) at tile boundary (lands B0-3,A0,A2 = needs of next phases 0-1);
// vmcnt(4) at end of phase 1 (lands A1,A3 = needs of phases 2-3). Never 0 in steady state.
template <int PHASE>
__global__ __launch_bounds__(512, 2) void conv_kernel(
    const __bf16* __restrict__ in,    // padded NHWC [8][130][130][256]
    const __bf16* __restrict__ wmall, // [8][256][9][256]
    float* __restrict__ outf,
    __bf16* __restrict__ outb) {
    __shared__ __bf16 sA[2][256 * 64];
    __shared__ __bf16 sB[2][256 * 64];
    const int tid  = threadIdx.x;
    const int bid  = blockIdx.x;
    // XCD-bijective swizzle: 512 blocks = 8 XCDs x 64; one batch per XCD.
    const int swz  = (bid & 7) * 64 + (bid >> 3);
    const int b    = swz >> 6;
    const int yt   = swz & 63;          // output row pair
    const int lane = tid & 63;
    const int wv   = tid >> 6;          // 0..7
    const int wo   = (wv >> 2) * 128;   // wave M offset
    const int wn   = (wv & 3) * 64;     // wave N offset
    const int arow = lane & 15;
    const int cgb  = lane >> 4;         // 0..3
    const int xA0  = (cgb ^ (arow & 7)) * 8;
    const int xA1  = xA0 ^ 32;
    // staging lane decomposition
    const int lr   = lane >> 3;
    const int lc   = lane & 7;
    const int swz8 = (lc ^ lr) * 8;
    const __bf16* wm_b = wmall + (size_t)b * 256 * 2304;

    size_t bOff[4], aOff[4];
#pragma unroll
    for (int q = 0; q < 4; ++q) {
        int r  = q * 64 + wv * 8 + lr;          // 0..255
        int pr = r >> 7, px = r & 127;
        bOff[q] = ((size_t)((b * 130 + yt * 2 + pr) * 130 + px)) * 256 + swz8;
        aOff[q] = (size_t)r * 2304 + swz8;
    }

    f32x4 acc[8][4] = {};
    bf16x8 bf[4][2];

    // prologue: stage K-tile 0 (tap=0 -> ky=kx=0, c0=0) into buffer 0
#pragma unroll
    for (int q = 0; q < 4; ++q) {
        GLDS(in + bOff[q],  &sB[0][(q * 64 + wv * 8) * 64]);
        GLDS(wm_b + aOff[q], &sA[0][(q * 64 + wv * 8) * 64]);
    }
    asm volatile("s_waitcnt vmcnt(0)" ::: "memory");
    __builtin_amdgcn_s_barrier();
    asm volatile("" ::: "memory");

    for (int t = 0; t < 36; ++t) {
        const __bf16* Ac = sA[t & 1];
        const __bf16* Bc = sB[t & 1];
        __bf16* An = sA[(t + 1) & 1];
        __bf16* Bn = sB[(t + 1) & 1];
        const bool st = (t < 35);
        const int nt = t + 1;
        const int ntap = nt >> 2, nc0 = (nt & 3) << 6;
        const int nky = ntap / 3, nkx = ntap - nky * 3;
        const size_t boff_t = (size_t)((nky * 130 + nkx) * 256 + nc0);
        const size_t aoff_t = (size_t)(ntap * 256 + nc0);

#define LOADA(qq, A00, A01, A10, A11)                                        \
        { const __bf16* ap0 = Ac + (wo + (2*(qq)) * 16 + arow) * 64;         \
          const __bf16* ap1 = Ac + (wo + (2*(qq)+1) * 16 + arow) * 64;       \
          A00 = *(const bf16x8*)(ap0 + xA0); A01 = *(const bf16x8*)(ap0 + xA1); \
          A10 = *(const bf16x8*)(ap1 + xA0); A11 = *(const bf16x8*)(ap1 + xA1); }

#define MFMAQ(M0, M1, A00, A01, A10, A11)                                    \
        _Pragma("unroll")                                                    \
        for (int j = 0; j < 4; ++j) {                                        \
            acc[M0][j] = MFMA(A00, bf[j][0], acc[M0][j]);                    \
            acc[M0][j] = MFMA(A01, bf[j][1], acc[M0][j]);                    \
            acc[M1][j] = MFMA(A10, bf[j][0], acc[M1][j]);                    \
            acc[M1][j] = MFMA(A11, bf[j][1], acc[M1][j]);                    \
        }

        // ---- phase 0 ----
        {
#pragma unroll
            for (int j = 0; j < 4; ++j) {
                const __bf16* bp = Bc + (wn + j * 16 + arow) * 64;
                bf[j][0] = *(const bf16x8*)(bp + xA0);
                bf[j][1] = *(const bf16x8*)(bp + xA1);
            }
            bf16x8 a00, a01, a10, a11;
            LOADA(0, a00, a01, a10, a11);
            if (st) {
                GLDS(in + bOff[0] + boff_t, &Bn[(0 * 64 + wv * 8) * 64]);
                GLDS(in + bOff[1] + boff_t, &Bn[(1 * 64 + wv * 8) * 64]);
            }
            __builtin_amdgcn_s_barrier();
            asm volatile("" ::: "memory");
            __builtin_amdgcn_s_setprio(1);
            MFMAQ(0, 1, a00, a01, a10, a11);
            __builtin_amdgcn_s_setprio(0);
            __builtin_amdgcn_s_barrier();
            asm volatile("" ::: "memory");
        }
        // ---- phase 1 ----
        {
            bf16x8 a00, a01, a10, a11;
            LOADA(1, a00, a01, a10, a11);
            if (st) {
                GLDS(in + bOff[2] + boff_t, &Bn[(2 * 64 + wv * 8) * 64]);
                GLDS(in + bOff[3] + boff_t, &Bn[(3 * 64 + wv * 8) * 64]);
            }
            __builtin_amdgcn_s_barrier();
            asm volatile("" ::: "memory");
            __builtin_amdgcn_s_setprio(1);
            MFMAQ(2, 3, a00, a01, a10, a11);
            __builtin_amdgcn_s_setprio(0);
            if (st) { asm volatile("s_waitcnt vmcnt(4)" ::: "memory"); }
            else    { asm volatile("s_waitcnt vmcnt(0)" ::: "memory"); }
            __builtin_amdgcn_s_barrier();
            asm volatile("" ::: "memory");
        }
        // ---- phase 2 ----
        {
            bf16x8 a00, a01, a10, a11;
            LOADA(2, a00, a01, a10, a11);
            if (st) {
                GLDS(wm_b + aOff[0] + aoff_t, &An[(0 * 64 + wv * 8) * 64]);
                GLDS(wm_b + aOff[2] + aoff_t, &An[(2 * 64 + wv * 8) * 64]);
            }
            __builtin_amdgcn_s_barrier();
            asm volatile("" ::: "memory");
            __builtin_amdgcn_s_setprio(1);
            MFMAQ(4, 5, a00, a01, a10, a11);
            __builtin_amdgcn_s_setprio(0);
            __builtin_amdgcn_s_barrier();
            asm volatile("" ::: "memory");
        }
        // ---- phase 3 ----
        {
            bf16x8 a00, a01, a10, a11;
            LOADA(3, a00, a01, a10, a11);
            if (st) {
                GLDS(wm_b + aOff[1] + aoff_t, &An[(1 * 64 + wv * 8) * 64]);
                GLDS(wm_b + aOff[3] + aoff_t, &An[(3 * 64 + wv * 8) * 64]);
            }
            __builtin_amdgcn_s_barrier();
            asm volatile("" ::: "memory");
            __builtin_amdgcn_s_setprio(1);
            MFMAQ(6, 7, a00, a01, a10, a11);
            __builtin_amdgcn_s_setprio(0);
            if (st) { asm volatile("s_waitcnt vmcnt(2)" ::: "memory"); }
            __builtin_amdgcn_s_barrier();
            asm volatile("" ::: "memory");
        }
#undef LOADA
#undef MFMAQ
    }

    // epilogue: leaky relu + store
#pragma unroll
    for (int m = 0; m < 8; ++m) {
#pragma unroll
        for (int j = 0; j < 4; ++j) {
            int o_base = wo + m * 16 + (lane >> 4) * 4;
            int n      = wn + j * 16 + (lane & 15);
            int pr = n >> 7, px = n & 127;
            if (PHASE == 1) {
                union { __bf16 v[4]; uint2 u; } pk;
#pragma unroll
                for (int r = 0; r < 4; ++r) {
                    float v = acc[m][j][r];
                    pk.v[r] = (__bf16)((v > 0.f) ? v : 0.2f * v);
                }
                *(uint2*)(outb + (((size_t)(b * 130) + yt * 2 + pr + 1) * 130 + px + 1) * 256 + o_base) = pk.u;
            } else {
#pragma unroll
                for (int r = 0; r < 4; ++r) {
                    float v = acc[m][j][r];
                    v = (v > 0.f) ? v : 0.2f * v;
                    outf[((size_t)(b * 256 + o_base + r) * 128 + yt * 2 + pr) * 128 + px] = v;
                }
            }
        }
    }
}

extern "C" void kernel_launch(void* const* d_in, const int* in_sizes, int n_in,
                              void* d_out, int out_size, void* d_ws, size_t ws_size,
                              hipStream_t stream) {
    const float* x      = (const float*)d_in[0];
    const float* istyle = (const float*)d_in[1];
    const float* ws1    = (const float*)d_in[2];
    const float* bs1    = (const float*)d_in[3];
    const float* w1     = (const float*)d_in[4];
    const float* ws2    = (const float*)d_in[5];
    const float* bs2    = (const float*)d_in[6];
    const float* w2     = (const float*)d_in[7];
    float* out = (float*)d_out;

    char* ws = (char*)d_ws;
    __bf16* xu_p = (__bf16*)(ws);
    __bf16* y1_p = (__bf16*)(ws + 69222400);
    __bf16* wm   = (__bf16*)(ws + 138444800);
    float*  sbuf = (float*)(ws + 147881984);

    style_kernel<<<dim3(8, 2), 256, 0, stream>>>(istyle, ws1, bs1, ws2, bs2, sbuf);
    zeropad_kernel<<<dim3(516, 8, 2), 32, 0, stream>>>(xu_p, y1_p);
    upsample_kernel<<<dim3(8, 128, 8), 256, 0, stream>>>(x, xu_p);
    modw_kernel<<<dim3(2048), 256, 0, stream>>>(w1, sbuf, wm);
    conv_kernel<1><<<dim3(512), 512, 0, stream>>>(xu_p, wm, nullptr, y1_p);
    modw_kernel<<<dim3(2048), 256, 0, stream>>>(w2, sbuf + 2048, wm);
    conv_kernel<2><<<dim3(512), 512, 0, stream>>>(y1_p, wm, out, nullptr);
}

// Round 4
// 379.548 us; speedup vs baseline: 1.5318x; 1.0478x over previous
//
#include <hip/hip_runtime.h>

typedef __bf16 bf16x8 __attribute__((ext_vector_type(8)));
typedef float f32x4 __attribute__((ext_vector_type(4)));

// ---------------- sizes ----------------
// B=8, LAT=512, CIN=F=256, Hin=Win=64, H=W=128, K=3
// ws layout (bytes):
//   xu_p NHWC bf16 [8][130][130][256] : off 0          size 69222400
//   y1_p NHWC bf16 [8][130][130][256] : off 69222400   size 69222400
//   wm   bf16 [8][256][9][256]        : off 138444800  size 9437184   (reused)
//   sbuf f32 [2][8][256]              : off 147881984  size 16384

#define GLDS(gsrc, ldst) __builtin_amdgcn_global_load_lds( \
    (const __attribute__((address_space(1))) unsigned int*)(gsrc), \
    (__attribute__((address_space(3))) unsigned int*)(ldst), 16, 0, 0)

#define MFMA(a, b, c) __builtin_amdgcn_mfma_f32_16x16x32_bf16((a), (b), (c), 0, 0, 0)

// ---------------- styles ----------------
__global__ void style_kernel(const float* __restrict__ istyle,
                             const float* __restrict__ ws1, const float* __restrict__ bs1,
                             const float* __restrict__ ws2, const float* __restrict__ bs2,
                             float* __restrict__ sbuf) {
    int b = blockIdx.x;
    int which = blockIdx.y;
    int c = threadIdx.x;
    const float* ws = which ? ws2 : ws1;
    const float* bs = which ? bs2 : bs1;
    __shared__ float st[512];
    for (int i = threadIdx.x; i < 512; i += 256) st[i] = istyle[b * 512 + i];
    __syncthreads();
    float acc = bs[c];
    const float* wr = ws + (size_t)c * 512;
    for (int l = 0; l < 512; ++l) acc += st[l] * wr[l];
    sbuf[((size_t)which * 8 + b) * 256 + c] = acc;
}

// ---------------- modulate + demodulate -> bf16 [b][o][tap][c] ----------------
__global__ void modw_kernel(const float* __restrict__ w, const float* __restrict__ s,
                            __bf16* __restrict__ wm) {
    int b = blockIdx.x >> 8;
    int o = blockIdx.x & 255;
    int c = threadIdx.x;
    float sm = s[(size_t)b * 256 + c] + 1.0f;
    float v[9];
    float ss = 0.f;
    const float* wr = w + ((size_t)o * 256 + c) * 9;
#pragma unroll
    for (int t = 0; t < 9; ++t) { v[t] = wr[t] * sm; ss += v[t] * v[t]; }
    __shared__ float red[256];
    red[c] = ss;
    __syncthreads();
    for (int sh = 128; sh > 0; sh >>= 1) {
        if (c < sh) red[c] += red[c + sh];
        __syncthreads();
    }
    float d = rsqrtf(red[0] + 1e-8f);
#pragma unroll
    for (int t = 0; t < 9; ++t)
        wm[(((size_t)(b * 256 + o) * 9 + t) * 256) + c] = (__bf16)(v[t] * d);
}

// ---------------- zero the 1-pixel border ----------------
__global__ void zeropad_kernel(__bf16* __restrict__ xu, __bf16* __restrict__ y1) {
    int p0 = blockIdx.x * 8;            // 8 perimeter pixels per block
    int b  = blockIdx.y;
    __bf16* buf = blockIdx.z ? y1 : xu;
    int p = p0 + (threadIdx.x >> 5);
    if (p >= 516) return;
    int chunk = threadIdx.x & 31;
    int y, x;
    if (p < 130)      { y = 0;           x = p; }
    else if (p < 260) { y = 129;         x = p - 130; }
    else if (p < 388) { y = p - 260 + 1; x = 0; }
    else              { y = p - 388 + 1; x = 129; }
    uint4 z = make_uint4(0, 0, 0, 0);
    *(uint4*)(buf + (((size_t)b * 130 + y) * 130 + x) * 256 + chunk * 8) = z;
}

// ---------------- bilinear 2x upsample NCHW f32 -> padded NHWC bf16 ----------------
__global__ void upsample_kernel(const float* __restrict__ x, __bf16* __restrict__ xu) {
    int ct = blockIdx.x;
    int y  = blockIdx.y;
    int b  = blockIdx.z;
    int c0 = ct * 32;
    __shared__ float up[32 * 132];
    int tid = threadIdx.x;

    int j = y >> 1;
    int y0, y1; float wy0, wy1;
    if (y & 1) { y0 = j; y1 = (j + 1 < 64) ? j + 1 : 63; wy0 = 0.75f; wy1 = 0.25f; }
    else       { y0 = (j - 1 >= 0) ? j - 1 : 0; y1 = j; wy0 = 0.25f; wy1 = 0.75f; }

    int c  = tid >> 3;
    int xs = (tid & 7) * 16;
    const float* row0 = x + ((size_t)(b * 256 + c0 + c) * 64 + y0) * 64;
    const float* row1 = x + ((size_t)(b * 256 + c0 + c) * 64 + y1) * 64;
#pragma unroll
    for (int k = 0; k < 16; ++k) {
        int xo = xs + k;
        int i = xo >> 1;
        int x0, x1; float wx0, wx1;
        if (xo & 1) { x0 = i; x1 = (i + 1 < 64) ? i + 1 : 63; wx0 = 0.75f; wx1 = 0.25f; }
        else        { x0 = (i - 1 >= 0) ? i - 1 : 0; x1 = i; wx0 = 0.25f; wx1 = 0.75f; }
        float v0 = wx0 * row0[x0] + wx1 * row0[x1];
        float v1 = wx0 * row1[x0] + wx1 * row1[x1];
        up[c * 132 + xo] = wy0 * v0 + wy1 * v1;
    }
    __syncthreads();
    int xo = tid >> 1, half = tid & 1;
    union { __bf16 v[8]; uint4 u; } pk;
#pragma unroll
    for (int g = 0; g < 2; ++g) {
#pragma unroll
        for (int i = 0; i < 8; ++i)
            pk.v[i] = (__bf16)up[(half * 16 + g * 8 + i) * 132 + xo];
        *(uint4*)(xu + (((size_t)(b * 130) + y + 1) * 130 + xo + 1) * 256 + c0 + half * 16 + g * 8) = pk.u;
    }
}

// ---------------- implicit-GEMM modulated conv, 256x256 tile, 8-phase schedule ----------------
// K-order: c0-major, tap-minor (t: tap=t%9, c0=(t/9)*64) so the block's 4 input rows x 64ch
// (66 KB) stay L2/L1-hot across all 9 taps -> staging loads are L2 hits.
// Per K-tile: 8 stage issues for tile t+1: ph0:{B0,B1} ph1:{B2,B3} ph2:{A0,A2} ph3:{A1,A3}.
// Counted waits: vmcnt(4) end of ph1 (lands A1,A3), vmcnt(2) end of ph3 (lands B0-3,A0,A2).
// PHASE 1 epilogue: LDS-transpose (reuse 128KB smem) -> contiguous 512B/pixel NHWC stores.
template <int PHASE>
__global__ __launch_bounds__(512, 2) void conv_kernel(
    const __bf16* __restrict__ in,    // padded NHWC [8][130][130][256]
    const __bf16* __restrict__ wmall, // [8][256][9][256]
    float* __restrict__ outf,
    __bf16* __restrict__ outb) {
    __shared__ __attribute__((aligned(128))) char smem[131072];
    __bf16* const sA0 = (__bf16*)smem;             // [2][256*64]
    __bf16* const sB0 = (__bf16*)(smem + 65536);   // [2][256*64]
    const int tid  = threadIdx.x;
    const int bid  = blockIdx.x;
    // XCD-bijective swizzle: 512 blocks = 8 XCDs x 64; one batch per XCD.
    const int swz  = (bid & 7) * 64 + (bid >> 3);
    const int b    = swz >> 6;
    const int yt   = swz & 63;          // output row pair
    const int lane = tid & 63;
    const int wv   = tid >> 6;          // 0..7
    const int wo   = (wv >> 2) * 128;   // wave M offset
    const int wn   = (wv & 3) * 64;     // wave N offset
    const int arow = lane & 15;
    const int cgb  = lane >> 4;         // 0..3
    const int xA0  = (cgb ^ (arow & 7)) * 8;
    const int xA1  = xA0 ^ 32;
    // staging lane decomposition
    const int lr   = lane >> 3;
    const int lc   = lane & 7;
    const int swz8 = (lc ^ lr) * 8;
    const __bf16* wm_b = wmall + (size_t)b * 256 * 2304;

    size_t bOff[4], aOff[4];
#pragma unroll
    for (int q = 0; q < 4; ++q) {
        int r  = q * 64 + wv * 8 + lr;          // 0..255
        int pr = r >> 7, px = r & 127;
        bOff[q] = ((size_t)((b * 130 + yt * 2 + pr) * 130 + px)) * 256 + swz8;
        aOff[q] = (size_t)r * 2304 + swz8;
    }

    f32x4 acc[8][4] = {};
    bf16x8 bf[4][2];

    // prologue: stage K-tile 0 (tap=0, c0=0) into buffer 0
#pragma unroll
    for (int q = 0; q < 4; ++q) {
        GLDS(in + bOff[q],   sB0 + (q * 64 + wv * 8) * 64);
        GLDS(wm_b + aOff[q], sA0 + (q * 64 + wv * 8) * 64);
    }
    asm volatile("s_waitcnt vmcnt(0)" ::: "memory");
    __builtin_amdgcn_s_barrier();
    asm volatile("" ::: "memory");

    for (int t = 0; t < 36; ++t) {
        const __bf16* Ac = sA0 + (t & 1) * 16384;
        const __bf16* Bc = sB0 + (t & 1) * 16384;
        __bf16* An = sA0 + ((t + 1) & 1) * 16384;
        __bf16* Bn = sB0 + ((t + 1) & 1) * 16384;
        const bool st = (t < 35);
        const int nt   = t + 1;
        const int ncb  = nt / 9;
        const int ntap = nt - 9 * ncb;
        const int nc0  = ncb * 64;
        const int nky  = ntap / 3, nkx = ntap - 3 * nky;
        const size_t boff_t = (size_t)((nky * 130 + nkx) * 256 + nc0);
        const size_t aoff_t = (size_t)(ntap * 256 + nc0);

#define LOADA(qq, A00, A01, A10, A11)                                        \
        { const __bf16* ap0 = Ac + (wo + (2*(qq)) * 16 + arow) * 64;         \
          const __bf16* ap1 = Ac + (wo + (2*(qq)+1) * 16 + arow) * 64;       \
          A00 = *(const bf16x8*)(ap0 + xA0); A01 = *(const bf16x8*)(ap0 + xA1); \
          A10 = *(const bf16x8*)(ap1 + xA0); A11 = *(const bf16x8*)(ap1 + xA1); }

#define MFMAQ(M0, M1, A00, A01, A10, A11)                                    \
        _Pragma("unroll")                                                    \
        for (int j = 0; j < 4; ++j) {                                        \
            acc[M0][j] = MFMA(A00, bf[j][0], acc[M0][j]);                    \
            acc[M0][j] = MFMA(A01, bf[j][1], acc[M0][j]);                    \
            acc[M1][j] = MFMA(A10, bf[j][0], acc[M1][j]);                    \
            acc[M1][j] = MFMA(A11, bf[j][1], acc[M1][j]);                    \
        }

        // ---- phase 0 ----
        {
#pragma unroll
            for (int j = 0; j < 4; ++j) {
                const __bf16* bp = Bc + (wn + j * 16 + arow) * 64;
                bf[j][0] = *(const bf16x8*)(bp + xA0);
                bf[j][1] = *(const bf16x8*)(bp + xA1);
            }
            bf16x8 a00, a01, a10, a11;
            LOADA(0, a00, a01, a10, a11);
            if (st) {
                GLDS(in + bOff[0] + boff_t, Bn + (0 * 64 + wv * 8) * 64);
                GLDS(in + bOff[1] + boff_t, Bn + (1 * 64 + wv * 8) * 64);
            }
            __builtin_amdgcn_s_barrier();
            asm volatile("" ::: "memory");
            __builtin_amdgcn_s_setprio(1);
            MFMAQ(0, 1, a00, a01, a10, a11);
            __builtin_amdgcn_s_setprio(0);
            __builtin_amdgcn_s_barrier();
            asm volatile("" ::: "memory");
        }
        // ---- phase 1 ----
        {
            bf16x8 a00, a01, a10, a11;
            LOADA(1, a00, a01, a10, a11);
            if (st) {
                GLDS(in + bOff[2] + boff_t, Bn + (2 * 64 + wv * 8) * 64);
                GLDS(in + bOff[3] + boff_t, Bn + (3 * 64 + wv * 8) * 64);
            }
            __builtin_amdgcn_s_barrier();
            asm volatile("" ::: "memory");
            __builtin_amdgcn_s_setprio(1);
            MFMAQ(2, 3, a00, a01, a10, a11);
            __builtin_amdgcn_s_setprio(0);
            if (st) { asm volatile("s_waitcnt vmcnt(4)" ::: "memory"); }
            else    { asm volatile("s_waitcnt vmcnt(0)" ::: "memory"); }
            __builtin_amdgcn_s_barrier();
            asm volatile("" ::: "memory");
        }
        // ---- phase 2 ----
        {
            bf16x8 a00, a01, a10, a11;
            LOADA(2, a00, a01, a10, a11);
            if (st) {
                GLDS(wm_b + aOff[0] + aoff_t, An + (0 * 64 + wv * 8) * 64);
                GLDS(wm_b + aOff[2] + aoff_t, An + (2 * 64 + wv * 8) * 64);
            }
            __builtin_amdgcn_s_barrier();
            asm volatile("" ::: "memory");
            __builtin_amdgcn_s_setprio(1);
            MFMAQ(4, 5, a00, a01, a10, a11);
            __builtin_amdgcn_s_setprio(0);
            __builtin_amdgcn_s_barrier();
            asm volatile("" ::: "memory");
        }
        // ---- phase 3 ----
        {
            bf16x8 a00, a01, a10, a11;
            LOADA(3, a00, a01, a10, a11);
            if (st) {
                GLDS(wm_b + aOff[1] + aoff_t, An + (1 * 64 + wv * 8) * 64);
                GLDS(wm_b + aOff[3] + aoff_t, An + (3 * 64 + wv * 8) * 64);
            }
            __builtin_amdgcn_s_barrier();
            asm volatile("" ::: "memory");
            __builtin_amdgcn_s_setprio(1);
            MFMAQ(6, 7, a00, a01, a10, a11);
            __builtin_amdgcn_s_setprio(0);
            if (st) { asm volatile("s_waitcnt vmcnt(2)" ::: "memory"); }
            __builtin_amdgcn_s_barrier();
            asm volatile("" ::: "memory");
        }
#undef LOADA
#undef MFMAQ
    }

    // pin all pending LDS reads / MFMAs before reusing smem (rule #18)
    __builtin_amdgcn_sched_barrier(0);
    __syncthreads();

    if (PHASE == 1) {
        // stage output tile [n=256 px][och=256] bf16 into LDS, XOR-swizzled rows
        __bf16* const ot = (__bf16*)smem;
        const int al = lane & 15;
        const int cg = lane >> 4;
#pragma unroll
        for (int m = 0; m < 8; ++m) {
#pragma unroll
            for (int j = 0; j < 4; ++j) {
                int n   = wn + j * 16 + al;
                int och = wo + m * 16 + cg * 4;
                union { __bf16 v[4]; uint2 u; } pk;
#pragma unroll
                for (int r = 0; r < 4; ++r) {
                    float v = acc[m][j][r];
                    pk.v[r] = (__bf16)((v > 0.f) ? v : 0.2f * v);
                }
                *(uint2*)((char*)ot + n * 512 + ((och * 2) ^ ((n & 7) << 4))) = pk.u;
            }
        }
        __syncthreads();
        // flush: per wave 32 pixels, 2 pixels/iter, contiguous 512B per pixel
        const int half = lane >> 5;
        const int l32  = lane & 31;
#pragma unroll
        for (int p = 0; p < 16; ++p) {
            int n  = wv * 32 + p * 2 + half;
            int pr = n >> 7, px = n & 127;
            uint4 v = *(const uint4*)((const char*)ot + n * 512 + ((l32 * 16) ^ ((n & 7) << 4)));
            *(uint4*)(outb + (((size_t)(b * 130) + yt * 2 + pr + 1) * 130 + px + 1) * 256 + l32 * 8) = v;
        }
    } else {
        // NCHW f32: 16 lanes x 4B = contiguous 64B lines, already fine
#pragma unroll
        for (int m = 0; m < 8; ++m) {
#pragma unroll
            for (int j = 0; j < 4; ++j) {
                int o_base = wo + m * 16 + (lane >> 4) * 4;
                int n      = wn + j * 16 + (lane & 15);
                int pr = n >> 7, px = n & 127;
#pragma unroll
                for (int r = 0; r < 4; ++r) {
                    float v = acc[m][j][r];
                    v = (v > 0.f) ? v : 0.2f * v;
                    outf[((size_t)(b * 256 + o_base + r) * 128 + yt * 2 + pr) * 128 + px] = v;
                }
            }
        }
    }
}

extern "C" void kernel_launch(void* const* d_in, const int* in_sizes, int n_in,
                              void* d_out, int out_size, void* d_ws, size_t ws_size,
                              hipStream_t stream) {
    const float* x      = (const float*)d_in[0];
    const float* istyle = (const float*)d_in[1];
    const float* ws1    = (const float*)d_in[2];
    const float* bs1    = (const float*)d_in[3];
    const float* w1     = (const float*)d_in[4];
    const float* ws2    = (const float*)d_in[5];
    const float* bs2    = (const float*)d_in[6];
    const float* w2     = (const float*)d_in[7];
    float* out = (float*)d_out;

    char* ws = (char*)d_ws;
    __bf16* xu_p = (__bf16*)(ws);
    __bf16* y1_p = (__bf16*)(ws + 69222400);
    __bf16* wm   = (__bf16*)(ws + 138444800);
    float*  sbuf = (float*)(ws + 147881984);

    style_kernel<<<dim3(8, 2), 256, 0, stream>>>(istyle, ws1, bs1, ws2, bs2, sbuf);
    zeropad_kernel<<<dim3(65, 8, 2), 256, 0, stream>>>(xu_p, y1_p);
    upsample_kernel<<<dim3(8, 128, 8), 256, 0, stream>>>(x, xu_p);
    modw_kernel<<<dim3(2048), 256, 0, stream>>>(w1, sbuf, wm);
    conv_kernel<1><<<dim3(512), 512, 0, stream>>>(xu_p, wm, nullptr, y1_p);
    modw_kernel<<<dim3(2048), 256, 0, stream>>>(w2, sbuf + 2048, wm);
    conv_kernel<2><<<dim3(512), 512, 0, stream>>>(y1_p, wm, out, nullptr);
}